// Round 2
// baseline (773.516 us; speedup 1.0000x reference)
//
#include <hip/hip_runtime.h>
#include <cstdint>
#include <cstddef>

// R2: full software pipeline (indices 2 ahead, A-gathers + stage DMA 1 ahead),
// consume barrier = vmcnt(2) (never drains store-acks), acc-merge folded into
// interp (+=), GRP=8, and d_ws/setup_kernel ELIMINATED (bfrag computed from W
// in-kernel) to test whether the 2x250us workspace poison fills disappear.
//
// All float inputs FP32, output FP32. bf16 only on the MFMA (t6 @ W) path.
#define Bb 2
#define Vv 4
#define Ff 128
#define Ee 128
#define NHh 7
#define N6c 196608
#define N5c 49152
#define N4c 12288
#define PFc 32768
#define P5c 8192
#define P4c 2048
#define GRP 8   // pc4 groups per block

typedef __attribute__((ext_vector_type(8))) short short8;
typedef __attribute__((ext_vector_type(4))) float f32x4;
typedef unsigned short u16;

// per-buffer LDS layout (float offsets)
#define OFF_T5 0        // 28 rows x 128
#define OFF_T4 3584     // 7 rows x 128
#define OFF_R4 4480     // 112 (rel4: [o4=16][nh=7])
#define OFF_R5 4592     // 112 (rel5: [p5l=4][o5=4][nh=7])
#define OFF_M4 4704     // 7 (+pad)
#define OFF_M5 4712     // 28 (+pad to 48)
#define BUFSZ  4752

__device__ __forceinline__ u16 f2bf(float f){
  union { float f; unsigned int i; } c; c.f = f;
  unsigned int x = c.i;
  return (u16)((x + 0x7fffu + ((x >> 16) & 1u)) >> 16);  // RNE fp32->bf16
}

__device__ __forceinline__ void gld16(const float* g, float* l){
  __builtin_amdgcn_global_load_lds(
      (const __attribute__((address_space(1))) unsigned int*)g,
      (__attribute__((address_space(3))) unsigned int*)l, 16, 0, 0);
}
__device__ __forceinline__ void gld4(const float* g, float* l){
  __builtin_amdgcn_global_load_lds(
      (const __attribute__((address_space(1))) unsigned int*)g,
      (__attribute__((address_space(3))) unsigned int*)l, 4, 0, 0);
}

// Consume barrier: vmcnt(2) — in-order retirement means all but the 2 newest
// VMEM ops (the g-1 output stores) are retired, which covers stage(g) DMA and
// the A/idx prefetches without ever waiting on store-acks.
#define BARC() asm volatile("s_waitcnt vmcnt(2) lgkmcnt(0)\n\ts_barrier" ::: "memory")
// LDS-only barrier: in-flight stage(g+1)/A(g+1) DMAs survive across it.
#define BARL() asm volatile("s_waitcnt lgkmcnt(0)\n\ts_barrier" ::: "memory")

__launch_bounds__(256, 3)
__global__ void mg_kernel(
    const float* __restrict__ t6, const float* __restrict__ t5, const float* __restrict__ t4,
    const float* __restrict__ W, const float* __restrict__ bias,
    const float* __restrict__ rel5, const float* __restrict__ rel4,
    const float* __restrict__ m5g, const float* __restrict__ m4g,
    const int* __restrict__ vidx, const int* __restrict__ idx6,
    const int* __restrict__ nh5, const int* __restrict__ nh4,
    float* __restrict__ out)
{
  __shared__ float sBuf[2][BUFSZ];   // double-buffered staged tiles (DMA dest, linear)
  __shared__ float sW4[16 * 8];
  __shared__ float sW5[16 * 8];
  __shared__ float sB[Ee];
  __shared__ float sOut[16 * 132];   // padded: acc scatter-write crosses rows

  const int tid = threadIdx.x;
  const int lane = tid & 63;
  const int wid = tid >> 6;
  const int m = lane & 15, q = lane >> 4;
  const int blk = blockIdx.x;
  const int bv = blk / (P4c / GRP);
  const int pbase = (blk % (P4c / GRP)) * GRP;
  const int v = bv % Vv, b = bv / Vv;
  const int vi = vidx[b * Vv + v];

  if (tid < Ee) sB[tid] = bias[tid];

  struct Pack { int id0, id1, id2, id3, id4, rowA; };

  // Gather-index prefetch (issued 1-2 iterations ahead of the stage that uses it).
  auto load_idx = [&](int pc) -> Pack {
    Pack p;
    int r0 = tid >> 5;                                 // t5 rows 0..7
    p.id0 = nh5[b * (P5c * NHh) + (pc * 4 + r0 / 7) * NHh + (r0 % 7)];
    int r1 = (tid + 256) >> 5;                         // 8..15
    p.id1 = nh5[b * (P5c * NHh) + (pc * 4 + r1 / 7) * NHh + (r1 % 7)];
    int r2 = (tid + 512) >> 5;                         // 16..23
    p.id2 = nh5[b * (P5c * NHh) + (pc * 4 + r2 / 7) * NHh + (r2 % 7)];
    if (tid < 128){
      int r3 = (tid + 768) >> 5;                       // 24..27
      p.id3 = nh5[b * (P5c * NHh) + (pc * 4 + r3 / 7) * NHh + (r3 % 7)];
    } else {
      p.id3 = nh4[b * (P4c * NHh) + pc * NHh + ((tid - 128) >> 5)];   // t4 rows 0..3
    }
    p.id4 = (tid < 96) ? nh4[b * (P4c * NHh) + pc * NHh + ((128 + tid) >> 5)] : 0; // rows 4..6
    p.rowA = idx6[b * PFc + pc * 16 + m];
    return p;
  };

  // Fire-and-forget DMA staging. Every issue site keeps active lanes starting
  // at lane 0 with dest = base + lane*size (gload_lds HW constraint, proven
  // pattern from prior rounds).
  auto stage = [&](float* buf, const Pack& p, int pc){
    const size_t b5 = (size_t)vi * N5c, b4 = (size_t)vi * N4c;
    const int c4 = (tid & 31) * 4;
    gld16(t5 + (b5 + p.id0) * Ff + c4, buf + OFF_T5 + tid * 4);
    gld16(t5 + (b5 + p.id1) * Ff + c4, buf + OFF_T5 + (tid + 256) * 4);
    gld16(t5 + (b5 + p.id2) * Ff + c4, buf + OFF_T5 + (tid + 512) * 4);
    if (tid < 128)
      gld16(t5 + (b5 + p.id3) * Ff + c4, buf + OFF_T5 + (tid + 768) * 4);
    else
      gld16(t4 + (b4 + p.id3) * Ff + c4, buf + OFF_T4 + (tid - 128) * 4);
    if (tid < 96)
      gld16(t4 + (b4 + p.id4) * Ff + c4, buf + OFF_T4 + (128 + tid) * 4);
    else if (tid >= 128 && tid < 156)   // rel4: 28 x 16B, wave2 lanes 0-27
      gld16(rel4 + (size_t)(b * P4c + pc) * 112 + (tid - 128) * 4, buf + OFF_R4 + (tid - 128) * 4);
    else if (tid >= 192 && tid < 220)   // rel5: 28 x 16B, wave3 lanes 0-27
      gld16(rel5 + (size_t)(b * P5c + pc * 4) * 28 + (tid - 192) * 4, buf + OFF_R5 + (tid - 192) * 4);
    if (tid < 7)                        // m4: 7 dwords, wave0 lanes 0-6
      gld4(m4g + (b * P4c + pc) * 7 + tid, buf + OFF_M4 + tid);
    else if (tid >= 64 && tid < 92)     // m5: 28 dwords, wave1 lanes 0-27
      gld4(m5g + (b * P5c + pc * 4) * 7 + (tid - 64), buf + OFF_M5 + (tid - 64));
  };

  // A-row gathers for the NEXT iteration live in-flight in these 32 VGPRs.
  f32x4 ra[8];
  auto issueA = [&](int rowA){
    const float* arow = t6 + ((size_t)vi * N6c + rowA) * Ff + q * 8;
#pragma unroll
    for (int kk = 0; kk < 4; kk++){
      ra[2 * kk]     = *(const f32x4*)(arow + kk * 32);
      ra[2 * kk + 1] = *(const f32x4*)(arow + kk * 32 + 4);
    }
  };

  // ---- prologue: fill pipeline ----
  Pack pk = load_idx(pbase);
  stage((float*)sBuf[0], pk, pbase);
  issueA(pk.rowA);
  Pack pkn = load_idx(pbase + 1);

  // bf16 W fragments computed in-kernel (d_ws unused; setup_kernel removed).
  // 64 scalar W loads/thread, once per block, L2-hot.
  short8 bfrag[2][4];
  {
    const int ntb = wid * 2;
#pragma unroll
    for (int i = 0; i < 2; i++)
#pragma unroll
      for (int kk = 0; kk < 4; kk++){
        short8 tf;
#pragma unroll
        for (int j = 0; j < 8; j++)
          tf[j] = (short)f2bf(W[(kk * 32 + q * 8 + j) * Ee + (ntb + i) * 16 + m]);
        bfrag[i][kk] = tf;
      }
  }

  for (int g = 0; g < GRP; g++){
    const int pc4 = pbase + g;
    const int cur = g & 1;
    const float* bufc = sBuf[cur];

    // convert ra(g) -> bf16 A fragments; compiler's vmcnt wait here also
    // implies (in-order retirement) that stage(g), issued earlier, is done.
    short8 af[4];
#pragma unroll
    for (int kk = 0; kk < 4; kk++){
      f32x4 lo = ra[2 * kk], hi = ra[2 * kk + 1];
      short8 cv;
#pragma unroll
      for (int j = 0; j < 4; j++){ cv[j] = (short)f2bf(lo[j]); cv[j + 4] = (short)f2bf(hi[j]); }
      af[kk] = cv;
    }

    BARC();   // stage(g) visible to all waves; g-1 stores may stay in flight

    // issue next-iteration loads immediately (hidden under MFMA/interp/store)
    if (g + 1 < GRP){
      stage((float*)sBuf[cur ^ 1], pkn, pc4 + 1);
      issueA(pkn.rowA);
    }
    if (g + 2 < GRP) pkn = load_idx(pc4 + 2);

    // ---- MFMA: 16 rows x 32 cols per wave ----
    f32x4 acc0 = {0.f,0.f,0.f,0.f}, acc1 = {0.f,0.f,0.f,0.f};
#pragma unroll
    for (int kk = 0; kk < 4; kk++){
      acc0 = __builtin_amdgcn_mfma_f32_16x16x32_bf16(af[kk], bfrag[0][kk], acc0, 0, 0, 0);
      acc1 = __builtin_amdgcn_mfma_f32_16x16x32_bf16(af[kk], bfrag[1][kk], acc1, 0, 0, 0);
    }

    // ---- acc + bias -> sOut (direct write; interp will +=) ----
    {
      int col = wid * 32 + m;
#pragma unroll
      for (int r = 0; r < 4; r++){
        int row = q * 4 + r;
        sOut[row * 132 + col]      = acc0[r] + sB[col];
        sOut[row * 132 + col + 16] = acc1[r] + sB[col + 16];
      }
    }

    // ---- weights from LDS-staged rel/mask (32 threads of wave 2) ----
    if (tid >= 128 && tid < 144){
      int t = tid - 128;
      const float* r4l = bufc + OFF_R4 + t * 7;
      const float* m4l = bufc + OFF_M4;
      float raw[7], s = 0.f;
#pragma unroll
      for (int n = 0; n < 7; n++){
        float rd = r4l[n] + m4l[n] * 1e10f;
        raw[n] = 1.0f / (1e-20f + rd); s += raw[n];
      }
      float inv = 1.0f / s;
#pragma unroll
      for (int n = 0; n < 7; n++) sW4[t * 8 + n] = raw[n] * inv;
    } else if (tid >= 144 && tid < 160){
      int t = tid - 144, p5l = t >> 2, o = t & 3;
      const float* r5l = bufc + OFF_R5 + p5l * 28 + o * 7;
      const float* m5l = bufc + OFF_M5 + p5l * 7;
      float raw[7], s = 0.f;
#pragma unroll
      for (int n = 0; n < 7; n++){
        float rd = r5l[n] + m5l[n] * 1e10f;
        raw[n] = 1.0f / (1e-20f + rd); s += raw[n];
      }
      float inv = 1.0f / s;
#pragma unroll
      for (int n = 0; n < 7; n++) sW5[t * 8 + n] = raw[n] * inv;
    }

    BARL();   // sOut(acc) + sW ready; prefetch DMAs stay in flight

    // ---- interp: += weighted neighbor rows (f32x4, within-row reads) ----
#pragma unroll
    for (int ii = 0; ii < 2; ii++){
      int k = tid + ii * 256;
      int t = k >> 5, ep = (k & 31) * 4;
      float* so = sOut + t * 132 + ep;
      f32x4 vv = *(const f32x4*)so;
      const float* w4p = sW4 + t * 8;
      const float* w5p = sW5 + t * 8;
      const float* p4 = bufc + OFF_T4 + ep;
      const float* p5 = bufc + OFF_T5 + (t >> 2) * 896 + ep;
#pragma unroll
      for (int n = 0; n < 7; n++){
        f32x4 a4 = *(const f32x4*)(p4 + n * 128);
        f32x4 a5 = *(const f32x4*)(p5 + n * 128);
        float w4 = w4p[n], w5 = w5p[n];
#pragma unroll
        for (int jj = 0; jj < 4; jj++) vv[jj] += w4 * a4[jj] + w5 * a5[jj];
      }
      *(f32x4*)so = vv;
    }

    BARL();   // tile complete

    // ---- coalesced nontemporal store: 16 rows x 512B ----
    {
      int tr = tid >> 4, c = (tid & 15) * 8;
      const float* sp = sOut + tr * 132 + c;
      size_t obase = (((size_t)bv) * PFc + (size_t)pc4 * 16 + tr) * Ee + c;
      f32x4 w0 = *(const f32x4*)sp;
      f32x4 w1 = *(const f32x4*)(sp + 4);
      __builtin_nontemporal_store(w0, (f32x4*)(out + obase));
      __builtin_nontemporal_store(w1, (f32x4*)(out + obase + 4));
    }
    // store ds_reads complete before next BARC (program order); sOut is only
    // rewritten after that barrier. Stores drain naturally (vmcnt(2) skips them).
  }
}

extern "C" void kernel_launch(void* const* d_in, const int* in_sizes, int n_in,
                              void* d_out, int out_size, void* d_ws, size_t ws_size,
                              hipStream_t stream){
  const float* t6   = (const float*)d_in[0];
  const float* t5   = (const float*)d_in[1];
  const float* t4   = (const float*)d_in[2];
  const float* W    = (const float*)d_in[3];
  const float* bias = (const float*)d_in[4];
  const float* rel5 = (const float*)d_in[5];
  const float* rel4 = (const float*)d_in[6];
  const float* m5   = (const float*)d_in[7];
  const float* m4   = (const float*)d_in[8];
  const int* vidx = (const int*)d_in[9];
  const int* idx6 = (const int*)d_in[10];
  const int* nh5  = (const int*)d_in[11];
  const int* nh4  = (const int*)d_in[12];

  (void)d_ws; (void)ws_size;   // workspace intentionally unused (R2 experiment)

  int grid = (Bb * Vv * P4c) / GRP;                // 2048 blocks x 256 threads
  mg_kernel<<<grid, 256, 0, stream>>>(t6, t5, t4, W, bias, rel5, rel4, m5, m4,
                                      vidx, idx6, nh5, nh4, (float*)d_out);
}